// Round 5
// baseline (265.530 us; speedup 1.0000x reference)
//
#include <hip/hip_runtime.h>
#include <hip/hip_fp16.h>
#include <stdint.h>

#define NN 100000
#define NE 1600000
#define DD 128
#define NTP 100032          // nodes padded to multiple of 64 (GEMM tiles)

#define BIN_SHIFT 5
#define BIN_ROWS 32
#define NBIN 3125           // 100000 / 32 exact
#define GCAP 1024           // per-bin edge capacity (mean 512, max ~650)
#define SPT 13              // scan items/thread: 13*256 = 3328 >= NBIN

typedef _Float16 f16x8 __attribute__((ext_vector_type(8)));
typedef float f32x4 __attribute__((ext_vector_type(4)));

__device__ __forceinline__ uint32_t hadd2u(uint32_t a, uint32_t b){
  union { uint32_t u; __half2 h; } x, y;
  x.u = a; y.u = b;
  x.h = __hadd2(x.h, y.h);
  return x.u;
}
__device__ __forceinline__ uint32_t hmul2u(uint32_t a, __half2 m){
  union { uint32_t u; __half2 h; } x; x.u = a;
  x.h = __hmul2(x.h, m);
  return x.u;
}

// ---- fused: x->f16 convert + per-edge histogram (global strided atomics)
//      tail blocks: W -> f16 frag-linear convert, agg pad zero ----
__global__ __launch_bounds__(256) void k_convhist(
    const float4* __restrict__ x, uint2* __restrict__ x16,
    const int* __restrict__ ei, int* __restrict__ g_hist,
    const float* __restrict__ w, uint16_t* __restrict__ wsw,
    uint32_t* __restrict__ aggpad){
  int b = blockIdx.x, t = threadIdx.x;
  int i = b*256 + t;
  if (i < NN*DD/4){                                  // 3.2M float4 -> f16x4
    float4 v = x[i];
    union { _Float16 h[4]; uint2 u; } r;
    r.h[0] = (_Float16)v.x; r.h[1] = (_Float16)v.y;
    r.h[2] = (_Float16)v.z; r.h[3] = (_Float16)v.w;
    x16[i] = r.u;
  } else if (b >= 12500 && b < 12564){               // W convert (16384 elems)
    int wi = (b - 12500)*256 + t;
    int j = wi & 7, l = (wi >> 3) & 63, kt = (wi >> 9) & 3, ct = wi >> 11;
    int k = kt*32 + ((l >> 4) & 3)*8 + j;
    int d = ct*16 + (l & 15);
    union { _Float16 h; uint16_t u; } cv; cv.h = (_Float16)w[k*DD + d];
    wsw[wi] = cv.u;
  } else if (b >= 12564){                            // agg pad rows (8 KB)
    aggpad[(b - 12564)*256 + t] = 0;
  }
  if (i < NE){                                       // per-edge histogram
    int r = ei[i];                                   // no self loops by construction
    atomicAdd(&g_hist[(r >> BIN_SHIFT)*16], 1);
  }
}

// ---- exclusive scan over NBIN bin counts (single 256-thread block) ----
__global__ void k_scan(const int* __restrict__ g_hist, int* __restrict__ bin_res,
                       int* __restrict__ bin_base){
  __shared__ int sd[256];
  int t = threadIdx.x;
  int base = t*SPT;
  int v[SPT]; int s = 0;
  #pragma unroll
  for (int j=0;j<SPT;j++){ int i = base+j; v[j] = (i < NBIN) ? g_hist[i*16] : 0; s += v[j]; }
  sd[t] = s; __syncthreads();
  for (int o=1;o<256;o<<=1){
    int y = (t >= o) ? sd[t-o] : 0;
    __syncthreads(); sd[t] += y; __syncthreads();
  }
  int run = sd[t] - s;
  #pragma unroll
  for (int j=0;j<SPT;j++){
    int i = base+j;
    if (i < NBIN){ bin_res[i*16] = run; bin_base[i] = run; }
    run += v[j];
  }
}

// ---- per-edge direct partition: one strided L2 atomic + one record write ----
__global__ __launch_bounds__(256) void k_part(const int* __restrict__ ei,
                                              int* __restrict__ bin_res,
                                              uint32_t* __restrict__ part){
  int b = blockIdx.x, t = threadIdx.x;
  #pragma unroll
  for (int k=0;k<4;k++){
    int e = b*1024 + k*256 + t;
    if (e < NE){
      int r = ei[e], c = ei[NE + e];
      int p = atomicAdd(&bin_res[(r >> BIN_SHIFT)*16], 1);
      part[p] = (uint32_t)(((r & 31) << 17) | c);
    }
  }
}

// ---- fused per-bin CSR build (LDS) + dual-edge f16 neighbor mean -> agg (MFMA-A frag) ----
__global__ __launch_bounds__(256) void k_bin_gather(
    const uint2* __restrict__ xp, const int* __restrict__ g_hist,
    const int* __restrict__ bin_base, const uint32_t* __restrict__ part,
    uint16_t* __restrict__ agg){
  __shared__ int s_col[GCAP];
  __shared__ int s_deg[BIN_ROWS], s_cur[BIN_ROWS];
  int t = threadIdx.x, wid = t >> 6, lane = t & 63;
  int b = blockIdx.x;
  int cnt = g_hist[b*16]; if (cnt > GCAP) cnt = GCAP;
  int base = bin_base[b];
  if (t < BIN_ROWS) s_deg[t] = 0;
  __syncthreads();
  for (int i=t; i<cnt; i+=256) atomicAdd(&s_deg[part[base+i] >> 17], 1);
  __syncthreads();
  if (wid == 0){
    int o = (lane < BIN_ROWS) ? s_deg[lane] : 0;
    int v = o;
    #pragma unroll
    for (int d=1; d<BIN_ROWS; d<<=1){ int y = __shfl_up(v, d); if (lane >= d) v += y; }
    if (lane < BIN_ROWS) s_cur[lane] = v - o;            // exclusive offset
  }
  __syncthreads();
  for (int i=t; i<cnt; i+=256){
    uint32_t rec = part[base+i];
    int p = atomicAdd(&s_cur[rec >> 17], 1);
    s_col[p] = (int)(rec & 0x1FFFF);
  }
  __syncthreads();
  int q = lane & 31, half = lane >> 5;                   // lanes 0-31 even edges, 32-63 odd
  int row0 = b << BIN_SHIFT;
  for (int lr = wid; lr < BIN_ROWS; lr += 4){
    int n = row0 + lr;                                   // NBIN*32 == NN: no guard needed
    int dg  = s_deg[lr];
    int off = s_cur[lr] - dg;                            // s_cur is now off+deg
    uint2 sv = xp[(size_t)n*32 + q];                     // self f16x4: dims 4q..4q+3
    uint32_t a01 = 0u, a23 = 0u;                         // packed f16x2 accumulators
    int j = 0;
    for (; j+16 <= dg; j += 16){                         // 8 dual loads in flight
      int c0 = s_col[off+j+half],    c1 = s_col[off+j+2+half];
      int c2 = s_col[off+j+4+half],  c3 = s_col[off+j+6+half];
      int c4 = s_col[off+j+8+half],  c5 = s_col[off+j+10+half];
      int c6 = s_col[off+j+12+half], c7 = s_col[off+j+14+half];
      uint2 v0 = xp[(size_t)c0*32 + q]; uint2 v1 = xp[(size_t)c1*32 + q];
      uint2 v2 = xp[(size_t)c2*32 + q]; uint2 v3 = xp[(size_t)c3*32 + q];
      uint2 v4 = xp[(size_t)c4*32 + q]; uint2 v5 = xp[(size_t)c5*32 + q];
      uint2 v6 = xp[(size_t)c6*32 + q]; uint2 v7 = xp[(size_t)c7*32 + q];
      a01 = hadd2u(a01, v0.x); a23 = hadd2u(a23, v0.y);
      a01 = hadd2u(a01, v1.x); a23 = hadd2u(a23, v1.y);
      a01 = hadd2u(a01, v2.x); a23 = hadd2u(a23, v2.y);
      a01 = hadd2u(a01, v3.x); a23 = hadd2u(a23, v3.y);
      a01 = hadd2u(a01, v4.x); a23 = hadd2u(a23, v4.y);
      a01 = hadd2u(a01, v5.x); a23 = hadd2u(a23, v5.y);
      a01 = hadd2u(a01, v6.x); a23 = hadd2u(a23, v6.y);
      a01 = hadd2u(a01, v7.x); a23 = hadd2u(a23, v7.y);
    }
    for (; j+8 <= dg; j += 8){
      int c0 = s_col[off+j+half],   c1 = s_col[off+j+2+half];
      int c2 = s_col[off+j+4+half], c3 = s_col[off+j+6+half];
      uint2 v0 = xp[(size_t)c0*32 + q]; uint2 v1 = xp[(size_t)c1*32 + q];
      uint2 v2 = xp[(size_t)c2*32 + q]; uint2 v3 = xp[(size_t)c3*32 + q];
      a01 = hadd2u(a01, v0.x); a23 = hadd2u(a23, v0.y);
      a01 = hadd2u(a01, v1.x); a23 = hadd2u(a23, v1.y);
      a01 = hadd2u(a01, v2.x); a23 = hadd2u(a23, v2.y);
      a01 = hadd2u(a01, v3.x); a23 = hadd2u(a23, v3.y);
    }
    for (; j+2 <= dg; j += 2){
      int c0 = s_col[off+j+half];
      uint2 v0 = xp[(size_t)c0*32 + q];
      a01 = hadd2u(a01, v0.x); a23 = hadd2u(a23, v0.y);
    }
    if (j < dg){                                         // odd tail: half 0 only
      int c0 = s_col[off+j];
      uint2 v0 = xp[(size_t)c0*32 + q];
      a01 = hadd2u(a01, half ? 0u : v0.x);
      a23 = hadd2u(a23, half ? 0u : v0.y);
    }
    a01 = hadd2u(a01, (uint32_t)__shfl_xor((int)a01, 32));
    a23 = hadd2u(a23, (uint32_t)__shfl_xor((int)a23, 32));
    __half2 inv2 = __float2half2_rn(1.0f / (float)(dg + 1));
    uint32_t r01 = hmul2u(hadd2u(a01, sv.x), inv2);      // dims (4q, 4q+1)
    uint32_t r23 = hmul2u(hadd2u(a23, sv.y), inv2);      // dims (4q+2, 4q+3)
    uint32_t pair = half ? r23 : r01;
    int k0 = q*4 + half*2;
    int kt = k0 >> 5, gk = (k0 >> 3) & 3, jj = k0 & 7;
    int ld = (n & 15) + (gk << 4);
    *(uint32_t*)(agg + ((((size_t)(n >> 4)*4 + kt)*64 + ld)*8 + jj)) = pair;
  }
}

// ---- LDS-free 16-row-per-wave GEMM (f16 MFMA) fused with row L2-normalize ----
__global__ __launch_bounds__(256) void k_gemm(const uint16_t* __restrict__ agg,
                                              const uint16_t* __restrict__ wsw,
                                              float* __restrict__ out){
  int tid = threadIdx.x, wid = tid >> 6, lane = tid & 63;
  int g = blockIdx.x*4 + wid;                            // 16-row group, g < 6252
  const f16x8* A = (const f16x8*)agg;
  const f16x8* B = (const f16x8*)wsw;
  size_t ab = (size_t)g*256 + lane;                      // frag units
  f16x8 a0 = A[ab], a1 = A[ab+64], a2 = A[ab+128], a3 = A[ab+192];

  f32x4 acc[8];
  #pragma unroll
  for (int ct=0;ct<8;ct++) acc[ct] = (f32x4){0.f,0.f,0.f,0.f};
  #pragma unroll
  for (int ct=0;ct<8;ct++){
    acc[ct] = __builtin_amdgcn_mfma_f32_16x16x32_f16(a0, B[(ct*4+0)*64 + lane], acc[ct], 0, 0, 0);
    acc[ct] = __builtin_amdgcn_mfma_f32_16x16x32_f16(a1, B[(ct*4+1)*64 + lane], acc[ct], 0, 0, 0);
    acc[ct] = __builtin_amdgcn_mfma_f32_16x16x32_f16(a2, B[(ct*4+2)*64 + lane], acc[ct], 0, 0, 0);
    acc[ct] = __builtin_amdgcn_mfma_f32_16x16x32_f16(a3, B[(ct*4+3)*64 + lane], acc[ct], 0, 0, 0);
  }

  float sq[4] = {0.f,0.f,0.f,0.f};
  #pragma unroll
  for (int ct=0;ct<8;ct++){
    #pragma unroll
    for (int i=0;i<4;i++) sq[i] += acc[ct][i]*acc[ct][i];
  }
  #pragma unroll
  for (int m=1;m<16;m<<=1){
    #pragma unroll
    for (int i=0;i<4;i++) sq[i] += __shfl_xor(sq[i], m);
  }
  float sc[4];
  #pragma unroll
  for (int i=0;i<4;i++) sc[i] = 1.0f / fmaxf(sqrtf(sq[i]), 1e-12f);

  int col = lane & 15;
  int rb = g*16 + ((lane >> 4) << 2);
  #pragma unroll
  for (int i=0;i<4;i++){
    int n = rb + i;
    if (n < NN){
      #pragma unroll
      for (int ct=0;ct<8;ct++)
        out[(size_t)n*DD + (ct<<4) + col] = acc[ct][i]*sc[i];
    }
  }
}

extern "C" void kernel_launch(void* const* d_in, const int* in_sizes, int n_in,
                              void* d_out, int out_size, void* d_ws, size_t ws_size,
                              hipStream_t stream){
  const float* x = (const float*)d_in[0];
  const int*  ei = (const int*)d_in[1];
  const float* w = (const float*)d_in[2];
  float* out = (float*)d_out;
  char* ws = (char*)d_ws;
  (void)in_sizes; (void)n_in; (void)out_size; (void)ws_size;

  size_t off = 0;
  uint16_t* x16 = (uint16_t*)(ws + off); off += (size_t)NN*DD*2;       // 25,600,000
  uint16_t* agg = (uint16_t*)(ws + off); off += (size_t)NTP*DD*2;      // 25,608,192
  uint16_t* wsw = (uint16_t*)(ws + off); off += (size_t)DD*DD*2;       // 32,768
  uint32_t* part = (uint32_t*)(ws + off); off += (size_t)NE*4;         // 6,400,000
  int* g_hist   = (int*)(ws + off); off += (size_t)NBIN*16*4;          // 200,000
  int* bin_res  = (int*)(ws + off); off += (size_t)NBIN*16*4;          // 200,000
  int* bin_base = (int*)(ws + off); off += (size_t)NBIN*4;             // 12,500  (~58.05 MB)

  uint32_t* aggpad = (uint32_t*)(agg + (size_t)NN*DD);                 // pad rows 100000..100031

  hipMemsetAsync(g_hist, 0, (size_t)NBIN*16*4, stream);
  k_convhist<<<12572, 256, 0, stream>>>((const float4*)x, (uint2*)x16, ei, g_hist,
                                        w, wsw, aggpad);
  k_scan<<<1, 256, 0, stream>>>(g_hist, bin_res, bin_base);
  k_part<<<1563, 256, 0, stream>>>(ei, bin_res, part);
  k_bin_gather<<<NBIN, 256, 0, stream>>>((const uint2*)x16, g_hist, bin_base, part, agg);
  k_gemm<<<1563, 256, 0, stream>>>(agg, wsw, out);
}

// Round 6
// 144.061 us; speedup vs baseline: 1.8432x; 1.8432x over previous
//
#include <hip/hip_runtime.h>
#include <hip/hip_fp16.h>
#include <stdint.h>

#define NN 100000
#define NE 1600000
#define DD 128
#define NTP 100032          // nodes padded to multiple of 64 (GEMM tiles)

#define NBKT 391            // buckets of 256 rows: 391*256 = 100096 >= NN
#define CAPB 4480           // per-bucket record capacity (mean 4096, sd ~64, +6sd)
#define GCAP 1024           // per-bin (32-row) staged col capacity (mean 512, max ~650)

typedef _Float16 f16x8 __attribute__((ext_vector_type(8)));
typedef float f32x4 __attribute__((ext_vector_type(4)));

__device__ __forceinline__ uint32_t hadd2u(uint32_t a, uint32_t b){
  union { uint32_t u; __half2 h; } x, y;
  x.u = a; y.u = b;
  x.h = __hadd2(x.h, y.h);
  return x.u;
}
__device__ __forceinline__ uint32_t hmul2u(uint32_t a, __half2 m){
  union { uint32_t u; __half2 h; } x; x.u = a;
  x.h = __hmul2(x.h, m);
  return x.u;
}

// ---- x (fp32) -> x16 (f16 linear); tail blocks: W -> f16 MFMA-frag-linear ----
__global__ __launch_bounds__(256) void k_convert(
    const float4* __restrict__ x, uint2* __restrict__ x16,
    const float* __restrict__ w, uint16_t* __restrict__ wsw){
  int b = blockIdx.x, t = threadIdx.x;
  if (b < 12500){
    int i = b*256 + t;                               // < 3.2M float4
    float4 v = x[i];
    union { _Float16 h[4]; uint2 u; } r;
    r.h[0] = (_Float16)v.x; r.h[1] = (_Float16)v.y;
    r.h[2] = (_Float16)v.z; r.h[3] = (_Float16)v.w;
    x16[i] = r.u;
  } else {
    int wi = (b - 12500)*256 + t;                    // < 16384
    int j = wi & 7, l = (wi >> 3) & 63, kt = (wi >> 9) & 3, ct = wi >> 11;
    int k = kt*32 + ((l >> 4) & 3)*8 + j;
    int d = ct*16 + (l & 15);
    union { _Float16 h; uint16_t u; } cv; cv.h = (_Float16)w[k*DD + d];
    wsw[wi] = cv.u;
  }
}

// ---- pass 1: partition edges into 391 fat buckets (dense ~42B chunks/block) ----
__global__ __launch_bounds__(256) void k_part1(const int* __restrict__ ei,
                                               int* __restrict__ bktres,
                                               uint32_t* __restrict__ ibuf){
  __shared__ int sh[NBKT];                           // hist, then global cursors
  int t = threadIdx.x;
  int e0 = blockIdx.x*4096;
  for (int i=t; i<NBKT; i+=256) sh[i] = 0;
  __syncthreads();
  int rr[16], cc[16];
  #pragma unroll
  for (int j=0;j<16;j++){
    int e = e0 + j*256 + t;
    rr[j] = -1;
    if (e < NE){
      rr[j] = ei[e]; cc[j] = ei[NE + e];             // no self loops by construction
      atomicAdd(&sh[rr[j] >> 8], 1);
    }
  }
  __syncthreads();
  for (int i=t; i<NBKT; i+=256){
    int v = sh[i];
    sh[i] = v ? atomicAdd(&bktres[i*16], v) : 0;     // reserve contiguous chunk per bucket
  }
  __syncthreads();
  #pragma unroll
  for (int j=0;j<16;j++){
    if (rr[j] >= 0){
      int bk = rr[j] >> 8;
      int p = atomicAdd(&sh[bk], 1);                 // global slot within bucket
      if (p < CAPB)
        ibuf[(size_t)bk*CAPB + p] = (uint32_t)(((rr[j] & 255) << 17) | cc[j]);
    }
  }
}

// ---- pass 2: sort each bucket by row in LDS; write cols back in-place + rowinfo ----
__global__ __launch_bounds__(256) void k_part2(const int* __restrict__ bktres,
                                               uint32_t* __restrict__ ibuf,
                                               uint32_t* __restrict__ rowinfo){
  __shared__ uint32_t s_rec[CAPB];                   // 17.9 KB
  __shared__ int s_deg[256], s_off[256], s_cur[256];
  int t = threadIdx.x, lane = t & 63, wid = t >> 6;
  int b = blockIdx.x;
  int cnt = bktres[b*16]; if (cnt > CAPB) cnt = CAPB;
  size_t bb = (size_t)b*CAPB;
  s_deg[t] = 0;
  __syncthreads();
  for (int i=t; i<cnt; i+=256){
    uint32_t rec = ibuf[bb + i];
    s_rec[i] = rec;
    atomicAdd(&s_deg[rec >> 17], 1);
  }
  __syncthreads();
  if (wid == 0){                                     // wave-0 scan of 256 degs
    int carry = 0;
    for (int ch=0; ch<4; ch++){
      int idx = ch*64 + lane;
      int o = s_deg[idx], v = o;
      #pragma unroll
      for (int d=1; d<64; d<<=1){ int y = __shfl_up(v, d); if (lane >= d) v += y; }
      int ex = carry + v - o;
      s_off[idx] = ex; s_cur[idx] = ex;
      carry += __shfl(v, 63);
    }
  }
  __syncthreads();
  int dgc = s_deg[t] > 255 ? 255 : s_deg[t];
  rowinfo[b*256 + t] = ((uint32_t)s_off[t] << 8) | (uint32_t)dgc;
  for (int i=t; i<cnt; i+=256){
    uint32_t rec = s_rec[i];
    int p = atomicAdd(&s_cur[rec >> 17], 1);
    ibuf[bb + p] = rec & 0x1FFFFu;                   // col only, row-sorted (L2-hot region)
  }
}

// ---- per-bin gather: stage sorted cols, dual-edge f16 neighbor mean -> agg (MFMA-A frag) ----
__global__ __launch_bounds__(256) void k_bin_gather(
    const uint2* __restrict__ xp, const uint32_t* __restrict__ ibuf,
    const uint32_t* __restrict__ rowinfo, uint16_t* __restrict__ agg){
  __shared__ int s_col[GCAP];
  __shared__ int s_loc[32], s_deg[32];
  int t = threadIdx.x, wid = t >> 6, lane = t & 63;
  int b = blockIdx.x;
  int row0 = b << 5;                                 // 32 rows, all in bucket row0>>8
  if (t < 32){
    uint32_t info = rowinfo[row0 + t];
    s_loc[t] = (int)(info >> 8);
    s_deg[t] = (int)(info & 255u);
  }
  __syncthreads();
  int base = s_loc[0];
  int len = s_loc[31] + s_deg[31] - base; if (len > GCAP) len = GCAP;
  size_t bb = (size_t)(row0 >> 8)*CAPB + base;
  for (int i=t; i<len; i+=256) s_col[i] = (int)ibuf[bb + i];
  __syncthreads();
  int q = lane & 31, half = lane >> 5;               // lanes 0-31 even edges, 32-63 odd
  for (int lr = wid; lr < 32; lr += 4){
    int n = row0 + lr;
    int dg  = s_deg[lr];
    int off = s_loc[lr] - base;
    uint2 sv = xp[(size_t)n*32 + q];                 // self f16x4: dims 4q..4q+3
    uint32_t a01 = 0u, a23 = 0u;                     // packed f16x2 accumulators
    int j = 0;
    for (; j+16 <= dg; j += 16){                     // 8 dual loads in flight
      int c0 = s_col[off+j+half],    c1 = s_col[off+j+2+half];
      int c2 = s_col[off+j+4+half],  c3 = s_col[off+j+6+half];
      int c4 = s_col[off+j+8+half],  c5 = s_col[off+j+10+half];
      int c6 = s_col[off+j+12+half], c7 = s_col[off+j+14+half];
      uint2 v0 = xp[(size_t)c0*32 + q]; uint2 v1 = xp[(size_t)c1*32 + q];
      uint2 v2 = xp[(size_t)c2*32 + q]; uint2 v3 = xp[(size_t)c3*32 + q];
      uint2 v4 = xp[(size_t)c4*32 + q]; uint2 v5 = xp[(size_t)c5*32 + q];
      uint2 v6 = xp[(size_t)c6*32 + q]; uint2 v7 = xp[(size_t)c7*32 + q];
      a01 = hadd2u(a01, v0.x); a23 = hadd2u(a23, v0.y);
      a01 = hadd2u(a01, v1.x); a23 = hadd2u(a23, v1.y);
      a01 = hadd2u(a01, v2.x); a23 = hadd2u(a23, v2.y);
      a01 = hadd2u(a01, v3.x); a23 = hadd2u(a23, v3.y);
      a01 = hadd2u(a01, v4.x); a23 = hadd2u(a23, v4.y);
      a01 = hadd2u(a01, v5.x); a23 = hadd2u(a23, v5.y);
      a01 = hadd2u(a01, v6.x); a23 = hadd2u(a23, v6.y);
      a01 = hadd2u(a01, v7.x); a23 = hadd2u(a23, v7.y);
    }
    for (; j+8 <= dg; j += 8){
      int c0 = s_col[off+j+half],   c1 = s_col[off+j+2+half];
      int c2 = s_col[off+j+4+half], c3 = s_col[off+j+6+half];
      uint2 v0 = xp[(size_t)c0*32 + q]; uint2 v1 = xp[(size_t)c1*32 + q];
      uint2 v2 = xp[(size_t)c2*32 + q]; uint2 v3 = xp[(size_t)c3*32 + q];
      a01 = hadd2u(a01, v0.x); a23 = hadd2u(a23, v0.y);
      a01 = hadd2u(a01, v1.x); a23 = hadd2u(a23, v1.y);
      a01 = hadd2u(a01, v2.x); a23 = hadd2u(a23, v2.y);
      a01 = hadd2u(a01, v3.x); a23 = hadd2u(a23, v3.y);
    }
    for (; j+2 <= dg; j += 2){
      int c0 = s_col[off+j+half];
      uint2 v0 = xp[(size_t)c0*32 + q];
      a01 = hadd2u(a01, v0.x); a23 = hadd2u(a23, v0.y);
    }
    if (j < dg){                                     // odd tail: half 0 only
      int c0 = s_col[off+j];
      uint2 v0 = xp[(size_t)c0*32 + q];
      a01 = hadd2u(a01, half ? 0u : v0.x);
      a23 = hadd2u(a23, half ? 0u : v0.y);
    }
    a01 = hadd2u(a01, (uint32_t)__shfl_xor((int)a01, 32));
    a23 = hadd2u(a23, (uint32_t)__shfl_xor((int)a23, 32));
    __half2 inv2 = __float2half2_rn(1.0f / (float)(dg + 1));
    uint32_t r01 = hmul2u(hadd2u(a01, sv.x), inv2);  // dims (4q, 4q+1)
    uint32_t r23 = hmul2u(hadd2u(a23, sv.y), inv2);  // dims (4q+2, 4q+3)
    uint32_t pair = half ? r23 : r01;
    int k0 = q*4 + half*2;
    int kt = k0 >> 5, gk = (k0 >> 3) & 3, jj = k0 & 7;
    int ld = (n & 15) + (gk << 4);
    *(uint32_t*)(agg + ((((size_t)(n >> 4)*4 + kt)*64 + ld)*8 + jj)) = pair;
  }
}

// ---- LDS-free 16-row-per-wave GEMM (f16 MFMA) fused with row L2-normalize ----
__global__ __launch_bounds__(256) void k_gemm(const uint16_t* __restrict__ agg,
                                              const uint16_t* __restrict__ wsw,
                                              float* __restrict__ out){
  int tid = threadIdx.x, wid = tid >> 6, lane = tid & 63;
  int g = blockIdx.x*4 + wid;                        // 16-row group, g < 6252
  const f16x8* A = (const f16x8*)agg;
  const f16x8* B = (const f16x8*)wsw;
  size_t ab = (size_t)g*256 + lane;                  // frag units
  f16x8 a0 = A[ab], a1 = A[ab+64], a2 = A[ab+128], a3 = A[ab+192];

  f32x4 acc[8];
  #pragma unroll
  for (int ct=0;ct<8;ct++) acc[ct] = (f32x4){0.f,0.f,0.f,0.f};
  #pragma unroll
  for (int ct=0;ct<8;ct++){
    acc[ct] = __builtin_amdgcn_mfma_f32_16x16x32_f16(a0, B[(ct*4+0)*64 + lane], acc[ct], 0, 0, 0);
    acc[ct] = __builtin_amdgcn_mfma_f32_16x16x32_f16(a1, B[(ct*4+1)*64 + lane], acc[ct], 0, 0, 0);
    acc[ct] = __builtin_amdgcn_mfma_f32_16x16x32_f16(a2, B[(ct*4+2)*64 + lane], acc[ct], 0, 0, 0);
    acc[ct] = __builtin_amdgcn_mfma_f32_16x16x32_f16(a3, B[(ct*4+3)*64 + lane], acc[ct], 0, 0, 0);
  }

  float sq[4] = {0.f,0.f,0.f,0.f};
  #pragma unroll
  for (int ct=0;ct<8;ct++){
    #pragma unroll
    for (int i=0;i<4;i++) sq[i] += acc[ct][i]*acc[ct][i];
  }
  #pragma unroll
  for (int m=1;m<16;m<<=1){
    #pragma unroll
    for (int i=0;i<4;i++) sq[i] += __shfl_xor(sq[i], m);
  }
  float sc[4];
  #pragma unroll
  for (int i=0;i<4;i++) sc[i] = 1.0f / fmaxf(sqrtf(sq[i]), 1e-12f);

  int col = lane & 15;
  int rb = g*16 + ((lane >> 4) << 2);
  #pragma unroll
  for (int i=0;i<4;i++){
    int n = rb + i;
    if (n < NN){
      #pragma unroll
      for (int ct=0;ct<8;ct++)
        out[(size_t)n*DD + (ct<<4) + col] = acc[ct][i]*sc[i];
    }
  }
}

extern "C" void kernel_launch(void* const* d_in, const int* in_sizes, int n_in,
                              void* d_out, int out_size, void* d_ws, size_t ws_size,
                              hipStream_t stream){
  const float* x = (const float*)d_in[0];
  const int*  ei = (const int*)d_in[1];
  const float* w = (const float*)d_in[2];
  float* out = (float*)d_out;
  char* ws = (char*)d_ws;
  (void)in_sizes; (void)n_in; (void)out_size; (void)ws_size;

  size_t off = 0;
  uint16_t* x16 = (uint16_t*)(ws + off); off += (size_t)NN*DD*2;         // 25,600,000
  uint16_t* agg = (uint16_t*)(ws + off); off += (size_t)NTP*DD*2;        // 25,608,192
  uint16_t* wsw = (uint16_t*)(ws + off); off += (size_t)DD*DD*2;         // 32,768
  uint32_t* ibuf = (uint32_t*)(ws + off); off += (size_t)NBKT*CAPB*4;    // 7,006,720
  int* bktres   = (int*)(ws + off); off += (size_t)NBKT*16*4;            // 25,024
  uint32_t* rowinfo = (uint32_t*)(ws + off); off += (size_t)NBKT*256*4;  // 400,384 (~58.67 MB)

  hipMemsetAsync(bktres, 0, (size_t)NBKT*16*4, stream);
  k_convert<<<12564, 256, 0, stream>>>((const float4*)x, (uint2*)x16, w, wsw);
  k_part1<<<391, 256, 0, stream>>>(ei, bktres, ibuf);
  k_part2<<<391, 256, 0, stream>>>(bktres, ibuf, rowinfo);
  k_bin_gather<<<3125, 256, 0, stream>>>((const uint2*)x16, ibuf, rowinfo, agg);
  k_gemm<<<1563, 256, 0, stream>>>(agg, wsw, out);
}

// Round 7
// 139.011 us; speedup vs baseline: 1.9101x; 1.0363x over previous
//
#include <hip/hip_runtime.h>
#include <hip/hip_fp16.h>
#include <stdint.h>

#define NN 100000
#define NE 1600000
#define DD 128

#define NBKT 391            // buckets of 256 rows: 391*256 = 100096 >= NN
#define CAPB 4480           // per-bucket record capacity (mean 4096, sd ~64, +6sd)
#define NBIN 3125           // 32-row bins: 3125*32 == NN exactly
#define GCAP 1024           // per-bin staged col capacity (mean 512, max ~650)

typedef _Float16 f16x8 __attribute__((ext_vector_type(8)));
typedef float f32x4 __attribute__((ext_vector_type(4)));

__device__ __forceinline__ uint32_t hadd2u(uint32_t a, uint32_t b){
  union { uint32_t u; __half2 h; } x, y;
  x.u = a; y.u = b;
  x.h = __hadd2(x.h, y.h);
  return x.u;
}
__device__ __forceinline__ uint32_t hmul2u(uint32_t a, __half2 m){
  union { uint32_t u; __half2 h; } x; x.u = a;
  x.h = __hmul2(x.h, m);
  return x.u;
}

// ---- front: blocks 0-390 partition edges into fat buckets; 391-12890 convert x;
//      12891-12954 convert W to MFMA-frag-linear f16 ----
__global__ __launch_bounds__(256) void k_front(
    const int* __restrict__ ei, int* __restrict__ bktres, uint32_t* __restrict__ ibuf,
    const float4* __restrict__ x, uint2* __restrict__ x16,
    const float* __restrict__ w, uint16_t* __restrict__ wsw){
  int b = blockIdx.x, t = threadIdx.x;
  if (b < NBKT){                                     // ---- part1 ----
    __shared__ int sh[NBKT];
    int e0 = b*4096;
    for (int i=t; i<NBKT; i+=256) sh[i] = 0;
    __syncthreads();
    int rr[16], cc[16];
    #pragma unroll
    for (int j=0;j<16;j++){
      int e = e0 + j*256 + t;
      rr[j] = -1;
      if (e < NE){
        rr[j] = ei[e]; cc[j] = ei[NE + e];           // no self loops by construction
        atomicAdd(&sh[rr[j] >> 8], 1);
      }
    }
    __syncthreads();
    for (int i=t; i<NBKT; i+=256){
      int v = sh[i];
      sh[i] = v ? atomicAdd(&bktres[i*16], v) : 0;   // reserve contiguous chunk
    }
    __syncthreads();
    #pragma unroll
    for (int j=0;j<16;j++){
      if (rr[j] >= 0){
        int bk = rr[j] >> 8;
        int p = atomicAdd(&sh[bk], 1);
        if (p < CAPB)
          ibuf[(size_t)bk*CAPB + p] = (uint32_t)(((rr[j] & 255) << 17) | cc[j]);
      }
    }
  } else if (b < 12891){                             // ---- x -> f16 ----
    int i = (b - NBKT)*256 + t;                      // < 3.2M float4
    float4 v = x[i];
    union { _Float16 h[4]; uint2 u; } r;
    r.h[0] = (_Float16)v.x; r.h[1] = (_Float16)v.y;
    r.h[2] = (_Float16)v.z; r.h[3] = (_Float16)v.w;
    x16[i] = r.u;
  } else {                                           // ---- W -> frag-linear f16 ----
    int wi = (b - 12891)*256 + t;                    // < 16384
    int j = wi & 7, l = (wi >> 3) & 63, kt = (wi >> 9) & 3, ct = wi >> 11;
    int k = kt*32 + ((l >> 4) & 3)*8 + j;
    int d = ct*16 + (l & 15);
    union { _Float16 h; uint16_t u; } cv; cv.h = (_Float16)w[k*DD + d];
    wsw[wi] = cv.u;
  }
}

// ---- pass 2: sort each bucket by row in LDS; write cols back in-place + rowinfo ----
__global__ __launch_bounds__(256) void k_part2(const int* __restrict__ bktres,
                                               uint32_t* __restrict__ ibuf,
                                               uint32_t* __restrict__ rowinfo){
  __shared__ uint32_t s_rec[CAPB];                   // 17.9 KB
  __shared__ int s_deg[256], s_off[256], s_cur[256];
  int t = threadIdx.x, lane = t & 63, wid = t >> 6;
  int b = blockIdx.x;
  int cnt = bktres[b*16]; if (cnt > CAPB) cnt = CAPB;
  size_t bb = (size_t)b*CAPB;
  s_deg[t] = 0;
  __syncthreads();
  for (int i=t; i<cnt; i+=256){
    uint32_t rec = ibuf[bb + i];
    s_rec[i] = rec;
    atomicAdd(&s_deg[rec >> 17], 1);
  }
  __syncthreads();
  if (wid == 0){                                     // wave-0 scan of 256 degs
    int carry = 0;
    for (int ch=0; ch<4; ch++){
      int idx = ch*64 + lane;
      int o = s_deg[idx], v = o;
      #pragma unroll
      for (int d=1; d<64; d<<=1){ int y = __shfl_up(v, d); if (lane >= d) v += y; }
      int ex = carry + v - o;
      s_off[idx] = ex; s_cur[idx] = ex;
      carry += __shfl(v, 63);
    }
  }
  __syncthreads();
  int dgc = s_deg[t] > 255 ? 255 : s_deg[t];
  rowinfo[b*256 + t] = ((uint32_t)s_off[t] << 8) | (uint32_t)dgc;
  for (int i=t; i<cnt; i+=256){
    uint32_t rec = s_rec[i];
    int p = atomicAdd(&s_cur[rec >> 17], 1);
    ibuf[bb + p] = rec & 0x1FFFFu;                   // col only, row-sorted, L2-hot
  }
}

// ---- fused: per-bin gather (32 rows) -> LDS frag tile -> MFMA gemm + L2-normalize ----
__global__ __launch_bounds__(256) void k_gather_gemm(
    const uint2* __restrict__ xp, const uint32_t* __restrict__ ibuf,
    const uint32_t* __restrict__ rowinfo, const uint16_t* __restrict__ wsw,
    float* __restrict__ out){
  __shared__ int s_col[GCAP];
  __shared__ int s_loc[32], s_deg[32];
  __shared__ uint16_t sAgg[4096];                    // 8 KB: 2 groups x 4 kt x 64 lanes x 8 f16
  __shared__ float sSq[2][2][4][4];                  // [group][ct-half][quarter][i]
  int t = threadIdx.x, wid = t >> 6, lane = t & 63;
  int b = blockIdx.x;
  int row0 = b << 5;
  if (t < 32){
    uint32_t info = rowinfo[row0 + t];
    s_loc[t] = (int)(info >> 8);
    s_deg[t] = (int)(info & 255u);
  }
  __syncthreads();
  int base = s_loc[0];
  int len = s_loc[31] + s_deg[31] - base; if (len > GCAP) len = GCAP;
  size_t bb = (size_t)(row0 >> 8)*CAPB + base;
  for (int i=t; i<len; i+=256) s_col[i] = (int)ibuf[bb + i];
  __syncthreads();

  int q = lane & 31, half = lane >> 5;               // lanes 0-31 even edges, 32-63 odd
  for (int lr = wid; lr < 32; lr += 4){
    int n = row0 + lr;
    int dg  = s_deg[lr];
    int off = s_loc[lr] - base;
    uint2 sv = xp[(size_t)n*32 + q];                 // self f16x4: dims 4q..4q+3
    uint32_t a01 = 0u, a23 = 0u;                     // packed f16x2 accumulators
    int j = 0;
    for (; j+32 <= dg; j += 32){                     // 16 dual loads in flight
      int cI[16];
      #pragma unroll
      for (int u=0; u<16; u++) cI[u] = s_col[off + j + 2*u + half];
      uint2 vI[16];
      #pragma unroll
      for (int u=0; u<16; u++) vI[u] = xp[(size_t)cI[u]*32 + q];
      #pragma unroll
      for (int u=0; u<16; u++){ a01 = hadd2u(a01, vI[u].x); a23 = hadd2u(a23, vI[u].y); }
    }
    for (; j+8 <= dg; j += 8){
      int c0 = s_col[off+j+half],   c1 = s_col[off+j+2+half];
      int c2 = s_col[off+j+4+half], c3 = s_col[off+j+6+half];
      uint2 v0 = xp[(size_t)c0*32 + q]; uint2 v1 = xp[(size_t)c1*32 + q];
      uint2 v2 = xp[(size_t)c2*32 + q]; uint2 v3 = xp[(size_t)c3*32 + q];
      a01 = hadd2u(a01, v0.x); a23 = hadd2u(a23, v0.y);
      a01 = hadd2u(a01, v1.x); a23 = hadd2u(a23, v1.y);
      a01 = hadd2u(a01, v2.x); a23 = hadd2u(a23, v2.y);
      a01 = hadd2u(a01, v3.x); a23 = hadd2u(a23, v3.y);
    }
    for (; j+2 <= dg; j += 2){
      int c0 = s_col[off+j+half];
      uint2 v0 = xp[(size_t)c0*32 + q];
      a01 = hadd2u(a01, v0.x); a23 = hadd2u(a23, v0.y);
    }
    if (j < dg){                                     // odd tail: half 0 only
      int c0 = s_col[off+j];
      uint2 v0 = xp[(size_t)c0*32 + q];
      a01 = hadd2u(a01, half ? 0u : v0.x);
      a23 = hadd2u(a23, half ? 0u : v0.y);
    }
    a01 = hadd2u(a01, (uint32_t)__shfl_xor((int)a01, 32));
    a23 = hadd2u(a23, (uint32_t)__shfl_xor((int)a23, 32));
    __half2 inv2 = __float2half2_rn(1.0f / (float)(dg + 1));
    uint32_t r01 = hmul2u(hadd2u(a01, sv.x), inv2);  // dims (4q, 4q+1)
    uint32_t r23 = hmul2u(hadd2u(a23, sv.y), inv2);  // dims (4q+2, 4q+3)
    uint32_t pair = half ? r23 : r01;
    int k0 = q*4 + half*2;
    int kt = k0 >> 5, gk = (k0 >> 3) & 3, jj = k0 & 7;
    int ld = (lr & 15) + (gk << 4);
    int lg = lr >> 4;
    *(uint32_t*)&sAgg[((lg*4 + kt)*64 + ld)*8 + jj] = pair;
  }
  __syncthreads();

  // ---- gemm phase: wave -> (group g2, ct-half ch); 16 MFMAs each ----
  int g2 = wid >> 1, ch = (wid & 1)*4;
  const f16x8* Bf = (const f16x8*)wsw;
  f16x8 a0 = *(const f16x8*)&sAgg[((g2*4+0)*64 + lane)*8];
  f16x8 a1 = *(const f16x8*)&sAgg[((g2*4+1)*64 + lane)*8];
  f16x8 a2 = *(const f16x8*)&sAgg[((g2*4+2)*64 + lane)*8];
  f16x8 a3 = *(const f16x8*)&sAgg[((g2*4+3)*64 + lane)*8];
  f32x4 acc[4];
  #pragma unroll
  for (int c2=0;c2<4;c2++) acc[c2] = (f32x4){0.f,0.f,0.f,0.f};
  #pragma unroll
  for (int c2=0;c2<4;c2++){
    acc[c2] = __builtin_amdgcn_mfma_f32_16x16x32_f16(a0, Bf[((ch+c2)*4+0)*64 + lane], acc[c2], 0, 0, 0);
    acc[c2] = __builtin_amdgcn_mfma_f32_16x16x32_f16(a1, Bf[((ch+c2)*4+1)*64 + lane], acc[c2], 0, 0, 0);
    acc[c2] = __builtin_amdgcn_mfma_f32_16x16x32_f16(a2, Bf[((ch+c2)*4+2)*64 + lane], acc[c2], 0, 0, 0);
    acc[c2] = __builtin_amdgcn_mfma_f32_16x16x32_f16(a3, Bf[((ch+c2)*4+3)*64 + lane], acc[c2], 0, 0, 0);
  }
  float sq[4] = {0.f,0.f,0.f,0.f};
  #pragma unroll
  for (int c2=0;c2<4;c2++){
    #pragma unroll
    for (int i=0;i<4;i++) sq[i] += acc[c2][i]*acc[c2][i];
  }
  #pragma unroll
  for (int m=1;m<16;m<<=1){
    #pragma unroll
    for (int i=0;i<4;i++) sq[i] += __shfl_xor(sq[i], m);
  }
  if ((lane & 15) == 0){
    #pragma unroll
    for (int i=0;i<4;i++) sSq[g2][wid & 1][lane >> 4][i] = sq[i];
  }
  __syncthreads();
  float sc[4];
  #pragma unroll
  for (int i=0;i<4;i++){
    float tot = sq[i] + sSq[g2][(wid & 1) ^ 1][lane >> 4][i];
    sc[i] = 1.0f / fmaxf(sqrtf(tot), 1e-12f);
  }
  int col = lane & 15;
  int rb = row0 + g2*16 + ((lane >> 4) << 2);        // rows: rb..rb+3 < NN always
  #pragma unroll
  for (int i=0;i<4;i++){
    int n = rb + i;
    #pragma unroll
    for (int c2=0;c2<4;c2++)
      out[(size_t)n*DD + (ch + c2)*16 + col] = acc[c2][i]*sc[i];
  }
}

extern "C" void kernel_launch(void* const* d_in, const int* in_sizes, int n_in,
                              void* d_out, int out_size, void* d_ws, size_t ws_size,
                              hipStream_t stream){
  const float* x = (const float*)d_in[0];
  const int*  ei = (const int*)d_in[1];
  const float* w = (const float*)d_in[2];
  float* out = (float*)d_out;
  char* ws = (char*)d_ws;
  (void)in_sizes; (void)n_in; (void)out_size; (void)ws_size;

  size_t off = 0;
  uint16_t* x16 = (uint16_t*)(ws + off); off += (size_t)NN*DD*2;         // 25,600,000
  uint16_t* wsw = (uint16_t*)(ws + off); off += (size_t)DD*DD*2;         // 32,768
  uint32_t* ibuf = (uint32_t*)(ws + off); off += (size_t)NBKT*CAPB*4;    // 7,006,720
  int* bktres   = (int*)(ws + off); off += (size_t)NBKT*16*4;            // 25,024
  uint32_t* rowinfo = (uint32_t*)(ws + off); off += (size_t)NBKT*256*4;  // 400,384 (~33 MB)

  hipMemsetAsync(bktres, 0, (size_t)NBKT*16*4, stream);
  k_front<<<12955, 256, 0, stream>>>(ei, bktres, ibuf, (const float4*)x, (uint2*)x16, w, wsw);
  k_part2<<<NBKT, 256, 0, stream>>>(bktres, ibuf, rowinfo);
  k_gather_gemm<<<NBIN, 256, 0, stream>>>((const uint2*)x16, ibuf, rowinfo, wsw, out);
}

// Round 8
// 136.436 us; speedup vs baseline: 1.9462x; 1.0189x over previous
//
#include <hip/hip_runtime.h>
#include <hip/hip_fp16.h>
#include <stdint.h>

#define NN 100000
#define NE 1600000
#define DD 128

#define NBKT 391            // buckets of 256 rows: 391*256 = 100096 >= NN
#define CAPB 4480           // per-bucket record capacity (mean 4096, sd ~64, +6sd)
#define NBIN 6250           // 16-row bins: 6250*16 == NN exactly
#define GCAP 512            // per-bin staged col capacity (mean 256, max ~340)

typedef _Float16 f16x8 __attribute__((ext_vector_type(8)));
typedef float f32x4 __attribute__((ext_vector_type(4)));

__device__ __forceinline__ uint32_t hadd2u(uint32_t a, uint32_t b){
  union { uint32_t u; __half2 h; } x, y;
  x.u = a; y.u = b;
  x.h = __hadd2(x.h, y.h);
  return x.u;
}
__device__ __forceinline__ uint32_t hmul2u(uint32_t a, __half2 m){
  union { uint32_t u; __half2 h; } x; x.u = a;
  x.h = __hmul2(x.h, m);
  return x.u;
}

// ---- front: blocks 0-390 partition edges into fat buckets; 391-12890 convert x;
//      12891-12954 convert W to MFMA-frag-linear f16 ----
__global__ __launch_bounds__(256) void k_front(
    const int* __restrict__ ei, int* __restrict__ bktres, uint32_t* __restrict__ ibuf,
    const float4* __restrict__ x, uint2* __restrict__ x16,
    const float* __restrict__ w, uint16_t* __restrict__ wsw){
  int b = blockIdx.x, t = threadIdx.x;
  if (b < NBKT){                                     // ---- part1 ----
    __shared__ int sh[NBKT];
    int e0 = b*4096;
    for (int i=t; i<NBKT; i+=256) sh[i] = 0;
    __syncthreads();
    int rr[16], cc[16];
    #pragma unroll
    for (int j=0;j<16;j++){
      int e = e0 + j*256 + t;
      rr[j] = -1;
      if (e < NE){
        rr[j] = ei[e]; cc[j] = ei[NE + e];           // no self loops by construction
        atomicAdd(&sh[rr[j] >> 8], 1);
      }
    }
    __syncthreads();
    for (int i=t; i<NBKT; i+=256){
      int v = sh[i];
      sh[i] = v ? atomicAdd(&bktres[i*16], v) : 0;   // reserve contiguous chunk
    }
    __syncthreads();
    #pragma unroll
    for (int j=0;j<16;j++){
      if (rr[j] >= 0){
        int bk = rr[j] >> 8;
        int p = atomicAdd(&sh[bk], 1);
        if (p < CAPB)
          ibuf[(size_t)bk*CAPB + p] = (uint32_t)(((rr[j] & 255) << 17) | cc[j]);
      }
    }
  } else if (b < 12891){                             // ---- x -> f16 ----
    int i = (b - NBKT)*256 + t;                      // < 3.2M float4
    float4 v = x[i];
    union { _Float16 h[4]; uint2 u; } r;
    r.h[0] = (_Float16)v.x; r.h[1] = (_Float16)v.y;
    r.h[2] = (_Float16)v.z; r.h[3] = (_Float16)v.w;
    x16[i] = r.u;
  } else {                                           // ---- W -> frag-linear f16 ----
    int wi = (b - 12891)*256 + t;                    // < 16384
    int j = wi & 7, l = (wi >> 3) & 63, kt = (wi >> 9) & 3, ct = wi >> 11;
    int k = kt*32 + ((l >> 4) & 3)*8 + j;
    int d = ct*16 + (l & 15);
    union { _Float16 h; uint16_t u; } cv; cv.h = (_Float16)w[k*DD + d];
    wsw[wi] = cv.u;
  }
}

// ---- pass 2: sort each bucket by row in LDS; write cols back in-place + rowinfo ----
__global__ __launch_bounds__(256) void k_part2(const int* __restrict__ bktres,
                                               uint32_t* __restrict__ ibuf,
                                               uint32_t* __restrict__ rowinfo){
  __shared__ uint32_t s_rec[CAPB];                   // 17.9 KB
  __shared__ int s_deg[256], s_off[256], s_cur[256];
  int t = threadIdx.x, lane = t & 63, wid = t >> 6;
  int b = blockIdx.x;
  int cnt = bktres[b*16]; if (cnt > CAPB) cnt = CAPB;
  size_t bb = (size_t)b*CAPB;
  s_deg[t] = 0;
  __syncthreads();
  for (int i=t; i<cnt; i+=256){
    uint32_t rec = ibuf[bb + i];
    s_rec[i] = rec;
    atomicAdd(&s_deg[rec >> 17], 1);
  }
  __syncthreads();
  if (wid == 0){                                     // wave-0 scan of 256 degs
    int carry = 0;
    for (int ch=0; ch<4; ch++){
      int idx = ch*64 + lane;
      int o = s_deg[idx], v = o;
      #pragma unroll
      for (int d=1; d<64; d<<=1){ int y = __shfl_up(v, d); if (lane >= d) v += y; }
      int ex = carry + v - o;
      s_off[idx] = ex; s_cur[idx] = ex;
      carry += __shfl(v, 63);
    }
  }
  __syncthreads();
  int dgc = s_deg[t] > 255 ? 255 : s_deg[t];
  rowinfo[b*256 + t] = ((uint32_t)s_off[t] << 8) | (uint32_t)dgc;
  for (int i=t; i<cnt; i+=256){
    uint32_t rec = s_rec[i];
    int p = atomicAdd(&s_cur[rec >> 17], 1);
    ibuf[bb + p] = rec & 0x1FFFFu;                   // col only, row-sorted, L2-hot
  }
}

// ---- fused: per-bin gather (16 rows, 2 waves) -> swizzled LDS frag tile -> MFMA + norm ----
__global__ __launch_bounds__(128, 6) void k_gather_gemm(
    const uint2* __restrict__ xp, const uint32_t* __restrict__ ibuf,
    const uint32_t* __restrict__ rowinfo, const uint16_t* __restrict__ wsw,
    float* __restrict__ out){
  __shared__ int s_col[GCAP];                        // 2 KB
  __shared__ int s_loc[16], s_deg[16];
  __shared__ uint32_t sAgg[1024];                    // 4 KB: 4 kt x 64 ld x 4 word (swizzled)
  int t = threadIdx.x, wid = t >> 6, lane = t & 63;
  int b = blockIdx.x;
  int row0 = b << 4;                                 // 16 rows, all inside bucket row0>>8
  if (t < 16){
    uint32_t info = rowinfo[row0 + t];
    s_loc[t] = (int)(info >> 8);
    s_deg[t] = (int)(info & 255u);
  }
  __syncthreads();
  int base = s_loc[0];
  int len = s_loc[15] + s_deg[15] - base; if (len > GCAP) len = GCAP;
  size_t bb = (size_t)(row0 >> 8)*CAPB + base;
  for (int i=t; i<len; i+=128) s_col[i] = (int)ibuf[bb + i];
  __syncthreads();

  int q = lane & 31, half = lane >> 5;               // lanes 0-31 even edges, 32-63 odd
  for (int lr = wid; lr < 16; lr += 2){
    int n = row0 + lr;
    int dg  = s_deg[lr];
    int off = s_loc[lr] - base;
    uint2 sv = xp[(size_t)n*32 + q];                 // self f16x4: dims 4q..4q+3
    uint32_t a01 = 0u, a23 = 0u;                     // packed f16x2 accumulators
    int j = 0;
    for (; j+8 <= dg; j += 8){                       // 4 dual loads in flight
      int c0 = s_col[off+j+half],   c1 = s_col[off+j+2+half];
      int c2 = s_col[off+j+4+half], c3 = s_col[off+j+6+half];
      uint2 v0 = xp[(size_t)c0*32 + q]; uint2 v1 = xp[(size_t)c1*32 + q];
      uint2 v2 = xp[(size_t)c2*32 + q]; uint2 v3 = xp[(size_t)c3*32 + q];
      a01 = hadd2u(a01, v0.x); a23 = hadd2u(a23, v0.y);
      a01 = hadd2u(a01, v1.x); a23 = hadd2u(a23, v1.y);
      a01 = hadd2u(a01, v2.x); a23 = hadd2u(a23, v2.y);
      a01 = hadd2u(a01, v3.x); a23 = hadd2u(a23, v3.y);
    }
    for (; j+2 <= dg; j += 2){
      int c0 = s_col[off+j+half];
      uint2 v0 = xp[(size_t)c0*32 + q];
      a01 = hadd2u(a01, v0.x); a23 = hadd2u(a23, v0.y);
    }
    if (j < dg){                                     // odd tail: half 0 only
      int c0 = s_col[off+j];
      uint2 v0 = xp[(size_t)c0*32 + q];
      a01 = hadd2u(a01, half ? 0u : v0.x);
      a23 = hadd2u(a23, half ? 0u : v0.y);
    }
    a01 = hadd2u(a01, (uint32_t)__shfl_xor((int)a01, 32));
    a23 = hadd2u(a23, (uint32_t)__shfl_xor((int)a23, 32));
    __half2 inv2 = __float2half2_rn(1.0f / (float)(dg + 1));
    uint32_t r01 = hmul2u(hadd2u(a01, sv.x), inv2);  // dims (4q, 4q+1)
    uint32_t r23 = hmul2u(hadd2u(a23, sv.y), inv2);  // dims (4q+2, 4q+3)
    uint32_t pair = half ? r23 : r01;
    int k0 = q*4 + half*2;
    int kt = k0 >> 5, gk = (k0 >> 3) & 3, jj = k0 & 7;
    int ld = lr + (gk << 4);
    int wdx = (kt*64 + ld)*4 + (jj >> 1);
    wdx ^= (kt << 3) ^ ((gk & 1) << 2);              // bank swizzle: 4 banks -> 32
    sAgg[wdx] = pair;
  }
  __syncthreads();

  // ---- gemm phase: each wave does its 16 rows x all 8 ct tiles ----
  const f16x8* Bf = (const f16x8*)wsw;
  f16x8 a[4];
  #pragma unroll
  for (int kt=0; kt<4; kt++){
    int wb = ((kt*64 + lane)*4) ^ (kt << 3) ^ (((lane >> 4) & 1) << 2);
    a[kt] = *(const f16x8*)&sAgg[wb];
  }
  f32x4 acc[8];
  #pragma unroll
  for (int ct=0;ct<8;ct++) acc[ct] = (f32x4){0.f,0.f,0.f,0.f};
  #pragma unroll
  for (int ct=0;ct<8;ct++){
    #pragma unroll
    for (int kt=0;kt<4;kt++)
      acc[ct] = __builtin_amdgcn_mfma_f32_16x16x32_f16(a[kt], Bf[(ct*4+kt)*64 + lane], acc[ct], 0, 0, 0);
  }
  float sq[4] = {0.f,0.f,0.f,0.f};
  #pragma unroll
  for (int ct=0;ct<8;ct++){
    #pragma unroll
    for (int i=0;i<4;i++) sq[i] += acc[ct][i]*acc[ct][i];
  }
  #pragma unroll
  for (int m=1;m<16;m<<=1){
    #pragma unroll
    for (int i=0;i<4;i++) sq[i] += __shfl_xor(sq[i], m);
  }
  float sc[4];
  #pragma unroll
  for (int i=0;i<4;i++) sc[i] = 1.0f / fmaxf(sqrtf(sq[i]), 1e-12f);

  int col = lane & 15;
  int rb = row0 + ((lane >> 4) << 2);                // all rows < NN (6250*16 == NN)
  #pragma unroll
  for (int i=0;i<4;i++){
    int n = rb + i;
    #pragma unroll
    for (int ct=0;ct<8;ct++)
      out[(size_t)n*DD + (ct<<4) + col] = acc[ct][i]*sc[i];
  }
}

extern "C" void kernel_launch(void* const* d_in, const int* in_sizes, int n_in,
                              void* d_out, int out_size, void* d_ws, size_t ws_size,
                              hipStream_t stream){
  const float* x = (const float*)d_in[0];
  const int*  ei = (const int*)d_in[1];
  const float* w = (const float*)d_in[2];
  float* out = (float*)d_out;
  char* ws = (char*)d_ws;
  (void)in_sizes; (void)n_in; (void)out_size; (void)ws_size;

  size_t off = 0;
  uint16_t* x16 = (uint16_t*)(ws + off); off += (size_t)NN*DD*2;         // 25,600,000
  uint16_t* wsw = (uint16_t*)(ws + off); off += (size_t)DD*DD*2;         // 32,768
  uint32_t* ibuf = (uint32_t*)(ws + off); off += (size_t)NBKT*CAPB*4;    // 7,006,720
  int* bktres   = (int*)(ws + off); off += (size_t)NBKT*16*4;            // 25,024
  uint32_t* rowinfo = (uint32_t*)(ws + off); off += (size_t)NBKT*256*4;  // 400,384 (~33 MB)

  hipMemsetAsync(bktres, 0, (size_t)NBKT*16*4, stream);
  k_front<<<12955, 256, 0, stream>>>(ei, bktres, ibuf, (const float4*)x, (uint2*)x16, w, wsw);
  k_part2<<<NBKT, 256, 0, stream>>>(bktres, ibuf, rowinfo);
  k_gather_gemm<<<NBIN, 128, 0, stream>>>((const uint2*)x16, ibuf, rowinfo, wsw, out);
}